// Round 1
// baseline (6545.492 us; speedup 1.0000x reference)
//
#include <hip/hip_runtime.h>
#include <hip/hip_fp16.h>

#define TSTEPS 15
#define HID    64
#define LAT    16
#define NBATCH 65536

// fast device transcendentals (err ~1e-7, negligible vs 1.8e-3 threshold)
__device__ __forceinline__ float fast_sig(float x) {
    return __builtin_amdgcn_rcpf(1.0f + __expf(-x));
}
__device__ __forceinline__ float fast_tanh(float x) {
    return 2.0f * __builtin_amdgcn_rcpf(1.0f + __expf(-2.0f * x)) - 1.0f;
}

// Thread-per-batch-element fused 2-layer LSTM + FC.
//  - weights/biases: wave-uniform indices -> scalar loads (SGPR broadcast)
//  - c0/c1: fp32 registers (all indexing static via full unroll of jc chunks)
//  - h0/x/h1: f16 in LDS, [k-pair][lane] layout (conflict-free, no barriers:
//    each thread touches only its own lane column)
//  - 3 LDS buffers rotate roles each step: (h0, x, h1) -> (x, h1, h0)
__global__ __launch_bounds__(64, 1) void lstm2_fused(
        const float* __restrict__ z,
        const float* __restrict__ Wih0, const float* __restrict__ Whh0,
        const float* __restrict__ bih0, const float* __restrict__ bhh0,
        const float* __restrict__ Wih1, const float* __restrict__ Whh1,
        const float* __restrict__ bih1, const float* __restrict__ bhh1,
        const float* __restrict__ Wfc,  const float* __restrict__ bfc,
        float* __restrict__ out)
{
    __shared__ __half2 hbuf[3][HID / 2][64];   // 3 x 8KB = 24KB per 64-thread block

    const int tid = threadIdx.x;
    const int b   = blockIdx.x * 64 + tid;

    // latent input, kept in registers (static indexing only)
    float zv[LAT];
#pragma unroll
    for (int k = 0; k < LAT; k += 4) {
        const float4 v = *reinterpret_cast<const float4*>(z + (size_t)b * LAT + k);
        zv[k] = v.x; zv[k + 1] = v.y; zv[k + 2] = v.z; zv[k + 3] = v.w;
    }

    float c0[HID], c1[HID];
#pragma unroll
    for (int j = 0; j < HID; ++j) { c0[j] = 0.0f; c1[j] = 0.0f; }

    const __half2 zero2 = __floats2half2_rn(0.0f, 0.0f);
#pragma unroll
    for (int kp = 0; kp < HID / 2; ++kp) {
        hbuf[0][kp][tid] = zero2;   // h0 = 0
        hbuf[2][kp][tid] = zero2;   // h1 = 0
    }

    int rh0 = 0, rx = 1, rh1 = 2;   // current h0 / x write-target / current h1

#pragma unroll 1
    for (int t = 0; t < TSTEPS; ++t) {
        /* ---------------- layer 0: x_new = LSTM0(z, h0) ---------------- */
#pragma unroll
        for (int jc = 0; jc < HID; jc += 4) {      // fully unrolled: c0 indices static
            float acc[4][4];                        // [gate q][unit u]
#pragma unroll
            for (int q = 0; q < 4; ++q)
#pragma unroll
                for (int u = 0; u < 4; ++u) {
                    const int g = q * HID + jc + u;
                    acc[q][u] = bih0[g] + bhh0[g];
                }
            // input projection from z (recomputed per step; z in regs)
#pragma unroll
            for (int k = 0; k < LAT; ++k) {
                const float xv = zv[k];
#pragma unroll
                for (int q = 0; q < 4; ++q)
#pragma unroll
                    for (int u = 0; u < 4; ++u)
                        acc[q][u] = fmaf(xv, Wih0[(q * HID + jc + u) * LAT + k], acc[q][u]);
            }
            // recurrent projection from h0 (f16 pairs out of LDS)
#pragma unroll 2
            for (int kp = 0; kp < HID / 2; ++kp) {
                const __half2 hp = hbuf[rh0][kp][tid];
                const float hlo = __low2float(hp);
                const float hhi = __high2float(hp);
#pragma unroll
                for (int q = 0; q < 4; ++q)
#pragma unroll
                    for (int u = 0; u < 4; ++u) {
                        const int g = q * HID + jc + u;
                        acc[q][u] = fmaf(hlo, Whh0[g * HID + 2 * kp],     acc[q][u]);
                        acc[q][u] = fmaf(hhi, Whh0[g * HID + 2 * kp + 1], acc[q][u]);
                    }
            }
            float hn[4];
#pragma unroll
            for (int u = 0; u < 4; ++u) {
                const float ig = fast_sig(acc[0][u]);
                const float fg = fast_sig(acc[1][u]);
                const float gg = fast_tanh(acc[2][u]);
                const float og = fast_sig(acc[3][u]);
                const float c  = fg * c0[jc + u] + ig * gg;
                c0[jc + u] = c;
                hn[u] = og * fast_tanh(c);
            }
            hbuf[rx][(jc >> 1) + 0][tid] = __floats2half2_rn(hn[0], hn[1]);
            hbuf[rx][(jc >> 1) + 1][tid] = __floats2half2_rn(hn[2], hn[3]);
        }

        /* -------- layer 1: h1_new = LSTM1(x_new, h1); fused FC -------- */
        float oacc = bfc[0];
#pragma unroll
        for (int jc = 0; jc < HID; jc += 4) {
            float acc[4][4];
#pragma unroll
            for (int q = 0; q < 4; ++q)
#pragma unroll
                for (int u = 0; u < 4; ++u) {
                    const int g = q * HID + jc + u;
                    acc[q][u] = bih1[g] + bhh1[g];
                }
#pragma unroll 2
            for (int kp = 0; kp < HID / 2; ++kp) {
                const __half2 xp = hbuf[rx][kp][tid];
                const __half2 hp = hbuf[rh1][kp][tid];
                const float xlo = __low2float(xp);
                const float xhi = __high2float(xp);
                const float hlo = __low2float(hp);
                const float hhi = __high2float(hp);
#pragma unroll
                for (int q = 0; q < 4; ++q)
#pragma unroll
                    for (int u = 0; u < 4; ++u) {
                        const int g = q * HID + jc + u;
                        acc[q][u] = fmaf(xlo, Wih1[g * HID + 2 * kp],     acc[q][u]);
                        acc[q][u] = fmaf(xhi, Wih1[g * HID + 2 * kp + 1], acc[q][u]);
                        acc[q][u] = fmaf(hlo, Whh1[g * HID + 2 * kp],     acc[q][u]);
                        acc[q][u] = fmaf(hhi, Whh1[g * HID + 2 * kp + 1], acc[q][u]);
                    }
            }
            float hn[4];
#pragma unroll
            for (int u = 0; u < 4; ++u) {
                const float ig = fast_sig(acc[0][u]);
                const float fg = fast_sig(acc[1][u]);
                const float gg = fast_tanh(acc[2][u]);
                const float og = fast_sig(acc[3][u]);
                const float c  = fg * c1[jc + u] + ig * gg;
                c1[jc + u] = c;
                hn[u] = og * fast_tanh(c);
                oacc = fmaf(hn[u], Wfc[jc + u], oacc);   // fused FC
            }
            // new h1 overwrites the (now dead) old-h0 buffer
            hbuf[rh0][(jc >> 1) + 0][tid] = __floats2half2_rn(hn[0], hn[1]);
            hbuf[rh0][(jc >> 1) + 1][tid] = __floats2half2_rn(hn[2], hn[3]);
        }

        out[(size_t)b * TSTEPS + t] = oacc;

        // rotate buffer roles: (h0, x, h1) <- (x, h1, h0_old)
        const int tmp = rh0;
        rh0 = rx; rx = rh1; rh1 = tmp;
    }
}

extern "C" void kernel_launch(void* const* d_in, const int* in_sizes, int n_in,
                              void* d_out, int out_size, void* d_ws, size_t ws_size,
                              hipStream_t stream)
{
    (void)in_sizes; (void)n_in; (void)out_size; (void)d_ws; (void)ws_size;

    const float* z    = (const float*)d_in[0];
    const float* Wih0 = (const float*)d_in[1];
    const float* Whh0 = (const float*)d_in[2];
    const float* bih0 = (const float*)d_in[3];
    const float* bhh0 = (const float*)d_in[4];
    const float* Wih1 = (const float*)d_in[5];
    const float* Whh1 = (const float*)d_in[6];
    const float* bih1 = (const float*)d_in[7];
    const float* bhh1 = (const float*)d_in[8];
    const float* Wfc  = (const float*)d_in[9];
    const float* bfc  = (const float*)d_in[10];

    lstm2_fused<<<dim3(NBATCH / 64), dim3(64), 0, stream>>>(
        z, Wih0, Whh0, bih0, bhh0, Wih1, Whh1, bih1, bhh1, Wfc, bfc,
        (float*)d_out);
}

// Round 2
// 850.527 us; speedup vs baseline: 7.6958x; 7.6958x over previous
//
#include <hip/hip_runtime.h>

#define TSTEPS 15
#define HID    64
#define LAT    16
#define NBATCH 65536

typedef _Float16 v8h __attribute__((ext_vector_type(8)));
typedef float    v4f __attribute__((ext_vector_type(4)));

__device__ __forceinline__ float fast_sig(float x) {
    return __builtin_amdgcn_rcpf(1.0f + __expf(-x));
}
__device__ __forceinline__ float fast_tanh(float x) {
    return 2.0f * __builtin_amdgcn_rcpf(1.0f + __expf(-2.0f * x)) - 1.0f;
}

__device__ __forceinline__ v8h vzero8() {
    v8h v;
#pragma unroll
    for (int i = 0; i < 8; ++i) v[i] = (_Float16)0.0f;
    return v;
}

// Fused 2-layer LSTM via MFMA, transposed orientation:
//   D[m=gate(256), n=batch(16)] = A[m][k] * B[k][n]
//   A = weights, staged in LDS as pre-swizzled 16x16x32 fragments.
//   B = inputs (z / h state), batch rides in lane&15 for B and C frags,
//       so the recurrent C->B transform is a wave-private LDS round-trip.
// Two phases per batch-tile (layer0 then layer1); x goes through d_ws as f16.
// Gate order (PyTorch): type 0=i,1=f,2=g,3=o ; g = 64*type + u, u=16a+4q+r.
__global__ __launch_bounds__(256, 2) void lstm2_mfma(
        const float* __restrict__ z,
        const float* __restrict__ Wih0, const float* __restrict__ Whh0,
        const float* __restrict__ bih0, const float* __restrict__ bhh0,
        const float* __restrict__ Wih1, const float* __restrict__ Whh1,
        const float* __restrict__ bih1, const float* __restrict__ bhh1,
        const float* __restrict__ Wfc,  const float* __restrict__ bfc,
        float* __restrict__ out,
        _Float16* __restrict__ xs,      // [512][15][64 rows][64 u] f16 in d_ws
        _Float16* __restrict__ wimg3)   // [16 mt][64 lane][8] kc3 frag image (ws)
{
    // A-fragment weights: [kc(3)][mt(16)][lane(64)][8 f16] = 49152 B
    __shared__ __align__(16) _Float16 wf[3 * 16 * 64 * 8];
    // per-wave h-state: [c(16)][u(64)+pad(8)] f16  -> 2304 B * 4 waves
    __shared__ __align__(16) _Float16 state[4][16 * 72];

    const int tid  = threadIdx.x;
    const int wave = tid >> 6;
    const int lane = tid & 63;
    const int q    = lane >> 4;      // quad
    const int c    = lane & 15;      // batch col within wave tile
    const int slot = blockIdx.x;     // 0..511

    _Float16* stW = &state[wave][0];
    const float bfcv = bfc[0];

#pragma unroll 1
    for (int tile = 0; tile < 2; ++tile) {
        const int rowblk = slot * 2 + tile;          // 0..1023
        const int row0   = rowblk * 64 + wave * 16;  // wave's global batch base

        /* ================== stage layer-0 weight fragments ================ */
        __syncthreads();   // wf may still be in use from previous phase/tile
#pragma unroll 4
        for (int e = tid; e < 3 * 16 * 64 * 8; e += 256) {
            const int j  = e & 7;
            const int lm = (e >> 3) & 63;
            const int mt = (e >> 9) & 15;
            const int kc = e >> 13;
            const int g  = mt * 16 + (lm & 15);
            const int k  = kc * 32 + (lm >> 4) * 8 + j;
            float v;
            if (kc == 0) v = (k < 16) ? Wih0[g * 16 + k] : 0.0f;  // z part (K=16, padded)
            else         v = Whh0[g * 64 + (k - 32)];             // h part u=k-32
            wf[e] = (_Float16)v;
        }
        __syncthreads();

        /* ========================= phase 1: layer 0 ======================= */
        {
            // z B-fragment (constant over t): B[k=8q+j][c] = z[row0+c][k], k<16
            v8h zfrag = vzero8();
            if (q < 2) {
                const float* zp = z + (size_t)(row0 + c) * LAT + q * 8;
                const float4 za = *(const float4*)(zp);
                const float4 zb = *(const float4*)(zp + 4);
                zfrag[0] = (_Float16)za.x; zfrag[1] = (_Float16)za.y;
                zfrag[2] = (_Float16)za.z; zfrag[3] = (_Float16)za.w;
                zfrag[4] = (_Float16)zb.x; zfrag[5] = (_Float16)zb.y;
                zfrag[6] = (_Float16)zb.z; zfrag[7] = (_Float16)zb.w;
            }

            v8h hf0 = vzero8(), hf1 = vzero8();   // h0 B-frags (u 0..31 / 32..63)
            float c0s[16];
#pragma unroll
            for (int i = 0; i < 16; ++i) c0s[i] = 0.0f;

#pragma unroll 1
            for (int t = 0; t < TSTEPS; ++t) {
#pragma unroll
                for (int a = 0; a < 4; ++a) {     // unit group u = 16a + 4q + r
                    v4f acc[4];
#pragma unroll
                    for (int ty = 0; ty < 4; ++ty) {
                        const int mt = 4 * ty + a;
                        const int g0 = 64 * ty + 16 * a + 4 * q;
                        const v4f bi = *(const v4f*)(bih0 + g0);
                        const v4f bh = *(const v4f*)(bhh0 + g0);
                        v4f t0 = bi + bh;         // fp32 bias in accumulator init
                        t0 = __builtin_amdgcn_mfma_f32_16x16x32_f16(
                                *(const v8h*)&wf[((0 * 16 + mt) * 64 + lane) * 8], zfrag, t0, 0, 0, 0);
                        t0 = __builtin_amdgcn_mfma_f32_16x16x32_f16(
                                *(const v8h*)&wf[((1 * 16 + mt) * 64 + lane) * 8], hf0, t0, 0, 0, 0);
                        t0 = __builtin_amdgcn_mfma_f32_16x16x32_f16(
                                *(const v8h*)&wf[((2 * 16 + mt) * 64 + lane) * 8], hf1, t0, 0, 0, 0);
                        acc[ty] = t0;
                    }
#pragma unroll
                    for (int r = 0; r < 4; ++r) {
                        const float ig = fast_sig(acc[0][r]);
                        const float fg = fast_sig(acc[1][r]);
                        const float gg = fast_tanh(acc[2][r]);
                        const float og = fast_sig(acc[3][r]);
                        const float cc = fg * c0s[a * 4 + r] + ig * gg;
                        c0s[a * 4 + r] = cc;
                        const float hh = og * fast_tanh(cc);
                        stW[c * 72 + 16 * a + 4 * q + r] = (_Float16)hh;
                    }
                }
                // read back h0' as B-frags (also the x_t fragment data)
                hf0 = *(const v8h*)&stW[c * 72 + 8 * q];
                hf1 = *(const v8h*)&stW[c * 72 + 32 + 8 * q];
                // store x_t to ws: [slot][t][lr][u]
                _Float16* xp = xs + (((size_t)(slot * TSTEPS + t) * 64) + wave * 16 + c) * 64;
                *(v8h*)(xp + 8 * q)      = hf0;
                *(v8h*)(xp + 32 + 8 * q) = hf1;
            }
        }

        /* ============= stage layer-1 weight fragments (+ kc3 image) ======= */
        __syncthreads();   // all waves done reading layer-0 wf
#pragma unroll 4
        for (int e = tid; e < 3 * 16 * 64 * 8; e += 256) {
            const int j  = e & 7;
            const int lm = (e >> 3) & 63;
            const int mt = (e >> 9) & 15;
            const int kc = e >> 13;
            const int g  = mt * 16 + (lm & 15);
            const int k  = kc * 32 + (lm >> 4) * 8 + j;
            float v;
            if (kc < 2) v = Wih1[g * 64 + k];           // x part k=0..63
            else        v = Whh1[g * 64 + (k - 64)];    // h part u=k-64 (0..31)
            wf[e] = (_Float16)v;
        }
#pragma unroll 4
        for (int e = tid; e < 16 * 64 * 8; e += 256) {  // kc3: Whh1 u=32..63
            const int j  = e & 7;
            const int lm = (e >> 3) & 63;
            const int mt = e >> 9;
            const int g  = mt * 16 + (lm & 15);
            const int k  = 96 + (lm >> 4) * 8 + j;
            wimg3[e] = (_Float16)Whh1[g * 64 + (k - 64)];
        }
        __syncthreads();

        /* ========================= phase 2: layer 1 ======================= */
        {
            v8h hf0 = vzero8(), hf1 = vzero8();   // h1 B-frags
            float c1s[16];
#pragma unroll
            for (int i = 0; i < 16; ++i) c1s[i] = 0.0f;

            const _Float16* xb = xs + (((size_t)(slot * TSTEPS) * 64) + wave * 16 + c) * 64;
            v8h xf0 = *(const v8h*)(xb + 8 * q);
            v8h xf1 = *(const v8h*)(xb + 32 + 8 * q);

#pragma unroll 1
            for (int t = 0; t < TSTEPS; ++t) {
                // prefetch next step's x frags
                v8h nxf0 = xf0, nxf1 = xf1;
                if (t + 1 < TSTEPS) {
                    const _Float16* xp = xs + (((size_t)(slot * TSTEPS + t + 1) * 64) + wave * 16 + c) * 64;
                    nxf0 = *(const v8h*)(xp + 8 * q);
                    nxf1 = *(const v8h*)(xp + 32 + 8 * q);
                }
                float p = 0.0f;   // FC partial
#pragma unroll
                for (int a = 0; a < 4; ++a) {
                    v4f acc[4];
#pragma unroll
                    for (int ty = 0; ty < 4; ++ty) {
                        const int mt = 4 * ty + a;
                        const int g0 = 64 * ty + 16 * a + 4 * q;
                        const v4f bi = *(const v4f*)(bih1 + g0);
                        const v4f bh = *(const v4f*)(bhh1 + g0);
                        const v8h w3 = *(const v8h*)(wimg3 + ((size_t)mt * 64 + lane) * 8);
                        v4f t0 = bi + bh;
                        t0 = __builtin_amdgcn_mfma_f32_16x16x32_f16(
                                *(const v8h*)&wf[((0 * 16 + mt) * 64 + lane) * 8], xf0, t0, 0, 0, 0);
                        t0 = __builtin_amdgcn_mfma_f32_16x16x32_f16(
                                *(const v8h*)&wf[((1 * 16 + mt) * 64 + lane) * 8], xf1, t0, 0, 0, 0);
                        t0 = __builtin_amdgcn_mfma_f32_16x16x32_f16(
                                *(const v8h*)&wf[((2 * 16 + mt) * 64 + lane) * 8], hf0, t0, 0, 0, 0);
                        t0 = __builtin_amdgcn_mfma_f32_16x16x32_f16(w3, hf1, t0, 0, 0, 0);
                        acc[ty] = t0;
                    }
                    const v4f wv = *(const v4f*)(Wfc + 16 * a + 4 * q);
#pragma unroll
                    for (int r = 0; r < 4; ++r) {
                        const float ig = fast_sig(acc[0][r]);
                        const float fg = fast_sig(acc[1][r]);
                        const float gg = fast_tanh(acc[2][r]);
                        const float og = fast_sig(acc[3][r]);
                        const float cc = fg * c1s[a * 4 + r] + ig * gg;
                        c1s[a * 4 + r] = cc;
                        const float hh = og * fast_tanh(cc);
                        stW[c * 72 + 16 * a + 4 * q + r] = (_Float16)hh;
                        p = fmaf(hh, wv[r], p);   // fused FC over u
                    }
                }
                hf0 = *(const v8h*)&stW[c * 72 + 8 * q];
                hf1 = *(const v8h*)&stW[c * 72 + 32 + 8 * q];
                // reduce FC partial across the 4 quads (u-space)
                p += __shfl_xor(p, 16);
                p += __shfl_xor(p, 32);
                if (lane < 16)
                    out[(size_t)(row0 + lane) * TSTEPS + t] = p + bfcv;
                xf0 = nxf0; xf1 = nxf1;
            }
        }
    }
}

extern "C" void kernel_launch(void* const* d_in, const int* in_sizes, int n_in,
                              void* d_out, int out_size, void* d_ws, size_t ws_size,
                              hipStream_t stream)
{
    (void)in_sizes; (void)n_in; (void)out_size; (void)ws_size;

    const float* z    = (const float*)d_in[0];
    const float* Wih0 = (const float*)d_in[1];
    const float* Whh0 = (const float*)d_in[2];
    const float* bih0 = (const float*)d_in[3];
    const float* bhh0 = (const float*)d_in[4];
    const float* Wih1 = (const float*)d_in[5];
    const float* Whh1 = (const float*)d_in[6];
    const float* bih1 = (const float*)d_in[7];
    const float* bhh1 = (const float*)d_in[8];
    const float* Wfc  = (const float*)d_in[9];
    const float* bfc  = (const float*)d_in[10];

    // ws layout: x scratch [512][15][64][64] f16 = 62,914,560 B, then kc3 frag
    // image 16 KB. Total need = 62,930,944 B.
    _Float16* xs    = (_Float16*)d_ws;
    _Float16* wimg3 = (_Float16*)((char*)d_ws + (size_t)512 * TSTEPS * 64 * 64 * 2);

    lstm2_mfma<<<dim3(512), dim3(256), 0, stream>>>(
        z, Wih0, Whh0, bih0, bhh0, Wih1, Whh1, bih1, bhh1, Wfc, bfc,
        (float*)d_out, xs, wimg3);
}